// Round 8
// baseline (294.643 us; speedup 1.0000x reference)
//
#include <hip/hip_runtime.h>
#include <hip/hip_bf16.h>

#define C 64              // C_IN == C_OUT == 64
#define KCH 128           // edge chunks (one block each)
#define RPP 12500         // rows per LDS pass (50 KB of u32 counters)

typedef unsigned short u16;

__device__ __forceinline__ u16 f2bf_rne(float v) {
    unsigned u = __float_as_uint(v);
    u += 0x7FFFu + ((u >> 16) & 1u);
    return (u16)(u >> 16);
}
__device__ __forceinline__ float bf2f(u16 u) {
    return __uint_as_float((unsigned)u << 16);
}

// --- Kernel 1: per-chunk LDS histogram. cnt16[k][r] = #edges of row r in
// chunk k; rank16[e] = intra-(chunk,row) rank (LDS atomic return).
__global__ __launch_bounds__(256) void hist_kernel(const int* __restrict__ row,
                                                   u16* __restrict__ cnt16,
                                                   u16* __restrict__ rank16,
                                                   int E, int N, int chunk) {
    __shared__ unsigned lcnt[RPP];
    int k = blockIdx.x;
    int t = threadIdx.x;
    int ebeg = k * chunk;
    int eend = min(E, ebeg + chunk);
    int passes = (N + RPP - 1) / RPP;
    for (int p = 0; p < passes; p++) {
        int rbase = p * RPP;
        int rcount = min(RPP, N - rbase);
        for (int i = t; i < rcount; i += 256) lcnt[i] = 0;
        __syncthreads();
        for (int e = ebeg + t; e < eend; e += 256) {
            unsigned rr = (unsigned)(row[e] - rbase);
            if (rr < (unsigned)rcount) {
                unsigned old = atomicAdd(&lcnt[rr], 1u);
                rank16[e] = (u16)old;
            }
        }
        __syncthreads();
        // dump counters, packed as u32 pairs (N, RPP even)
        unsigned* dst = (unsigned*)(cnt16 + (size_t)k * N + rbase);
        int pairs = rcount >> 1;
        for (int i = t; i < pairs; i += 256)
            dst[i] = (lcnt[2 * i] & 0xffffu) | (lcnt[2 * i + 1] << 16);
        if ((rcount & 1) && t == 0)
            cnt16[(size_t)k * N + rbase + rcount - 1] = (u16)lcnt[rcount - 1];
        __syncthreads();
    }
}

// --- Scan A: per-row totals over chunks + per-block (512-row) sums ---
__global__ __launch_bounds__(256) void scanA_kernel(const u16* __restrict__ cnt16,
                                                    int* __restrict__ cnttot,
                                                    int* __restrict__ bsum,
                                                    int N, int K) {
    __shared__ int s[256];
    int t = threadIdx.x;
    int base = blockIdx.x * 512;
    int r0 = base + 2 * t, r1 = r0 + 1;
    int tot0 = 0, tot1 = 0;
    for (int k = 0; k < K; k++) {
        if (r0 < N) {
            size_t o = (size_t)k * N + r0;
            if (r1 < N) {
                unsigned v = *(const unsigned*)(cnt16 + o);
                tot0 += (int)(v & 0xffffu);
                tot1 += (int)(v >> 16);
            } else {
                tot0 += (int)cnt16[o];
            }
        }
    }
    if (r0 < N) cnttot[r0] = tot0;
    if (r1 < N) cnttot[r1] = tot1;
    s[t] = tot0 + tot1;
    __syncthreads();
    for (int off = 128; off > 0; off >>= 1) {
        if (t < off) s[t] += s[t + off];
        __syncthreads();
    }
    if (t == 0) bsum[blockIdx.x] = s[0];
}

// --- Scan B: exclusive scan of G (<=256) block sums; writes rowptr[N] ---
__global__ __launch_bounds__(256) void scanB_kernel(int* __restrict__ bsum,
                                                    int* __restrict__ rowptr,
                                                    int G, int N) {
    __shared__ int s[256];
    int t = threadIdx.x;
    int v = (t < G) ? bsum[t] : 0;
    s[t] = v;
    __syncthreads();
    for (int off = 1; off < 256; off <<= 1) {
        int u = (t >= off) ? s[t - off] : 0;
        __syncthreads();
        s[t] += u;
        __syncthreads();
    }
    if (t < G) bsum[t] = s[t] - v;
    if (t == 255) rowptr[N] = s[255];
}

// --- Scan C: rowptr + absolute per-chunk slot bases prefix32[k][r] ---
__global__ __launch_bounds__(256) void scanC_kernel(const u16* __restrict__ cnt16,
                                                    const int* __restrict__ cnttot,
                                                    const int* __restrict__ bsum,
                                                    int* __restrict__ rowptr,
                                                    unsigned* __restrict__ prefix32,
                                                    int N, int K) {
    __shared__ int s[256];
    int t = threadIdx.x;
    int base = blockIdx.x * 512;
    int r0 = base + 2 * t, r1 = r0 + 1;
    int v0 = (r0 < N) ? cnttot[r0] : 0;
    int v1 = (r1 < N) ? cnttot[r1] : 0;
    int pair = v0 + v1;
    s[t] = pair;
    __syncthreads();
    for (int off = 1; off < 256; off <<= 1) {
        int u = (t >= off) ? s[t - off] : 0;
        __syncthreads();
        s[t] += u;
        __syncthreads();
    }
    int ex = bsum[blockIdx.x] + s[t] - pair;   // exclusive prefix for r0
    int rp0 = ex, rp1 = ex + v0;
    if (r0 < N) rowptr[r0] = rp0;
    if (r1 < N) rowptr[r1] = rp1;
    unsigned run0 = (unsigned)rp0, run1 = (unsigned)rp1;
    for (int k = 0; k < K; k++) {
        size_t o = (size_t)k * N + r0;
        if (r0 < N) {
            if (r1 < N) {
                unsigned v = *(const unsigned*)(cnt16 + o);
                uint2 pr; pr.x = run0; pr.y = run1;
                *(uint2*)(prefix32 + o) = pr;
                run0 += (v & 0xffffu);
                run1 += (v >> 16);
            } else {
                unsigned v = cnt16[o];
                prefix32[o] = run0;
                run0 += v;
            }
        }
    }
}

// --- Kernel 4: atomic-free scatter: pos = prefix32[k][r] + rank16[e].
// Stores RAW (ew, col) — normalization factored out via dis.
__global__ __launch_bounds__(256) void scatter_kernel(const int* __restrict__ row,
                                                      const int* __restrict__ col,
                                                      const float* __restrict__ ew,
                                                      const u16* __restrict__ rank16,
                                                      const unsigned* __restrict__ prefix32,
                                                      float2* __restrict__ ewc,
                                                      int E, int N, int chunk) {
    int k = blockIdx.x;
    int t = threadIdx.x;
    int ebeg = k * chunk;
    int eend = min(E, ebeg + chunk);
    size_t kb = (size_t)k * N;
    for (int g = ebeg; g < eend; g += 1024) {
        int e[4]; unsigned pos[4]; int cc[4]; float wv[4];
#pragma unroll
        for (int u = 0; u < 4; u++) {
            e[u] = g + u * 256 + t;
            if (e[u] < eend) {
                int r = row[e[u]];
                pos[u] = prefix32[kb + r] + rank16[e[u]];
                cc[u] = col[e[u]];
                wv[u] = ew[e[u]];
            }
        }
#pragma unroll
        for (int u = 0; u < 4; u++)
            if (e[u] < eend) ewc[pos[u]] = make_float2(wv[u], __int_as_float(cc[u]));
    }
}

// --- Kernel 5: deg from CSR row-sums -> dis; g = bf16(dis .* x) ---
__global__ __launch_bounds__(256) void degdis_kernel(const int* __restrict__ rowptr,
                                                     const float2* __restrict__ ewc,
                                                     const float* __restrict__ x,
                                                     float* __restrict__ dis,
                                                     u16* __restrict__ g,
                                                     int N) {
    __shared__ float sdis[256];
    int t = threadIdx.x;
    int r = blockIdx.x * 256 + t;
    if (r < N) {
        int b = rowptr[r], en = rowptr[r + 1];
        float dv = 0.0f;
        for (int p = b; p < en; p++) dv += ewc[p].x;
        float di = (dv > 0.0f) ? rsqrtf(dv) : 0.0f;
        dis[r] = di;
        sdis[t] = di;
    }
    __syncthreads();
    // scale 256 rows x 64 ch = 4096 float4
    size_t nb = (size_t)blockIdx.x * 16384;
    for (int i = 0; i < 16; i++) {
        int idx4 = i * 256 + t;          // 0..4095
        int lr = idx4 >> 4;              // local row
        int gr = blockIdx.x * 256 + lr;
        if (gr < N) {
            float4 v = *(const float4*)(x + nb + (size_t)idx4 * 4);
            float di = sdis[lr];
            ushort4 o;
            o.x = f2bf_rne(v.x * di); o.y = f2bf_rne(v.y * di);
            o.z = f2bf_rne(v.z * di); o.w = f2bf_rne(v.w * di);
            *(ushort4*)(g + nb + (size_t)idx4 * 4) = o;
        }
    }
}

// --- Kernel 6: CSR SpMM with factored normalization.
// S = sum_e ew_e * h[col_e];  out32 = -dis_r*S;  outbf = bf16(dis_r*out32).
__global__ __launch_bounds__(256) void spmm_csr_kernel(
        const int* __restrict__ rowptr,
        const float2* __restrict__ ewc,
        const float* __restrict__ dis,
        const u16* __restrict__ h,        // bf16 [N][C], pre-scaled by dis
        float* __restrict__ out32,        // fp32 [N][C]
        u16* __restrict__ outbf,          // bf16 [N][C] (dis-scaled, for next prop)
        int N, int writebf) {
    int wid = (blockIdx.x * blockDim.x + threadIdx.x) >> 6;
    int lane = threadIdx.x & 63;
    if (wid >= N) return;
    int beg = rowptr[wid];
    int end = rowptr[wid + 1];
    float a0 = 0.0f, a1 = 0.0f, a2 = 0.0f, a3 = 0.0f;
    for (int base = beg; base < end; base += 64) {
        int idx = base + lane;
        float2 ed = (idx < end) ? ewc[idx] : make_float2(0.0f, 0.0f);
        int cnt = end - base; if (cnt > 64) cnt = 64;
        int j = 0;
        for (; j + 3 < cnt; j += 4) {
            float w0 = __int_as_float(__builtin_amdgcn_readlane(__float_as_int(ed.x), j));
            int   c0 = __builtin_amdgcn_readlane(__float_as_int(ed.y), j);
            float w1 = __int_as_float(__builtin_amdgcn_readlane(__float_as_int(ed.x), j + 1));
            int   c1 = __builtin_amdgcn_readlane(__float_as_int(ed.y), j + 1);
            float w2 = __int_as_float(__builtin_amdgcn_readlane(__float_as_int(ed.x), j + 2));
            int   c2 = __builtin_amdgcn_readlane(__float_as_int(ed.y), j + 2);
            float w3 = __int_as_float(__builtin_amdgcn_readlane(__float_as_int(ed.x), j + 3));
            int   c3 = __builtin_amdgcn_readlane(__float_as_int(ed.y), j + 3);
            float h0 = bf2f(h[(size_t)c0 * C + lane]);
            float h1 = bf2f(h[(size_t)c1 * C + lane]);
            float h2 = bf2f(h[(size_t)c2 * C + lane]);
            float h3 = bf2f(h[(size_t)c3 * C + lane]);
            a0 = fmaf(w0, h0, a0);
            a1 = fmaf(w1, h1, a1);
            a2 = fmaf(w2, h2, a2);
            a3 = fmaf(w3, h3, a3);
        }
        for (; j < cnt; j++) {
            float w0 = __int_as_float(__builtin_amdgcn_readlane(__float_as_int(ed.x), j));
            int   c0 = __builtin_amdgcn_readlane(__float_as_int(ed.y), j);
            a0 = fmaf(w0, bf2f(h[(size_t)c0 * C + lane]), a0);
        }
    }
    float dr = dis[wid];
    float res = -dr * ((a0 + a1) + (a2 + a3));
    size_t o = (size_t)wid * C + lane;
    out32[o] = res;
    if (writebf) outbf[o] = f2bf_rne(dr * res);
}

// --- Kernel 7: fused dense epilogue as register-tiled GEMM ---
// out = relu([x | T1 | 2P-x] @ Wcat + b), Wcat = [192][64] (W row-major)
__global__ __launch_bounds__(256) void final_gemm_kernel(
        const float* __restrict__ x,
        const float* __restrict__ T1,
        const float* __restrict__ P,
        const float* __restrict__ W,   // [192][64] row-major
        const float* __restrict__ b,
        float* __restrict__ out, int N) {
    __shared__ float As[16][64];  // [k][node]
    __shared__ float Ws[16][64];  // [k][col]

    int t  = threadIdx.x;
    int tx = t & 15;
    int ty = t >> 4;
    int n0 = blockIdx.x * 64;

    int sn = t >> 2;
    int skb = (t & 3) * 4;

    float acc[4][4];
#pragma unroll
    for (int i = 0; i < 4; i++)
#pragma unroll
        for (int j = 0; j < 4; j++) acc[i][j] = 0.0f;

#pragma unroll 1
    for (int s = 0; s < 12; s++) {
        float4 wv = *(const float4*)(W + s * 1024 + t * 4);
        int nn = n0 + sn;
        float4 av = make_float4(0.f, 0.f, 0.f, 0.f);
        if (nn < N) {
            if (s < 4) {
                av = *(const float4*)(x + (size_t)nn * C + s * 16 + skb);
            } else if (s < 8) {
                av = *(const float4*)(T1 + (size_t)nn * C + (s - 4) * 16 + skb);
            } else {
                float4 pv = *(const float4*)(P + (size_t)nn * C + (s - 8) * 16 + skb);
                float4 xv = *(const float4*)(x + (size_t)nn * C + (s - 8) * 16 + skb);
                av = make_float4(2.0f * pv.x - xv.x, 2.0f * pv.y - xv.y,
                                 2.0f * pv.z - xv.z, 2.0f * pv.w - xv.w);
            }
        }
        __syncthreads();
        {
            int wk = (t * 4) >> 6;
            int wc = (t * 4) & 63;
            *(float4*)&Ws[wk][wc] = wv;
        }
        As[skb + 0][sn] = av.x;
        As[skb + 1][sn] = av.y;
        As[skb + 2][sn] = av.z;
        As[skb + 3][sn] = av.w;
        __syncthreads();

#pragma unroll
        for (int kk = 0; kk < 16; kk++) {
            float4 a4 = *(const float4*)&As[kk][ty * 4];
            float4 w4 = *(const float4*)&Ws[kk][tx * 4];
            float ar[4] = {a4.x, a4.y, a4.z, a4.w};
            float wr[4] = {w4.x, w4.y, w4.z, w4.w};
#pragma unroll
            for (int i = 0; i < 4; i++)
#pragma unroll
                for (int j = 0; j < 4; j++)
                    acc[i][j] = fmaf(ar[i], wr[j], acc[i][j]);
        }
    }

    float4 bv = *(const float4*)(b + tx * 4);
    float br[4] = {bv.x, bv.y, bv.z, bv.w};
#pragma unroll
    for (int i = 0; i < 4; i++) {
        int node = n0 + ty * 4 + i;
        if (node < N) {
            float4 o;
            o.x = fmaxf(acc[i][0] + br[0], 0.0f);
            o.y = fmaxf(acc[i][1] + br[1], 0.0f);
            o.z = fmaxf(acc[i][2] + br[2], 0.0f);
            o.w = fmaxf(acc[i][3] + br[3], 0.0f);
            *(float4*)(out + (size_t)node * C + tx * 4) = o;
        }
    }
}

extern "C" void kernel_launch(void* const* d_in, const int* in_sizes, int n_in,
                              void* d_out, int out_size, void* d_ws, size_t ws_size,
                              hipStream_t stream) {
    const float* x  = (const float*)d_in[0];
    const int*   ei = (const int*)d_in[1];
    const float* ew = (const float*)d_in[2];
    const float* W  = (const float*)d_in[3];
    const float* b  = (const float*)d_in[4];
    float* out = (float*)d_out;

    const int N = in_sizes[0] / C;
    const int E = in_sizes[2];
    const int* row = ei;        // edge_index[0]
    const int* col = ei + E;    // edge_index[1]

    char* ws = (char*)d_ws;
    size_t off = 0;
    auto alloc = [&](size_t bytes) {
        void* p = ws + off;
        off = (off + bytes + 255) & ~(size_t)255;
        return p;
    };
    float*    dis      = (float*)alloc((size_t)N * 4);
    int*      cnttot   = (int*)alloc((size_t)N * 4);
    int*      rowptr   = (int*)alloc((size_t)(N + 1) * 4);
    float2*   ewc      = (float2*)alloc((size_t)E * 8);
    float*    T1       = (float*)alloc((size_t)N * C * 4);
    float*    P        = (float*)alloc((size_t)N * C * 4);
    int*      bsum     = (int*)alloc((size_t)256 * 4);
    u16*      cnt16    = (u16*)alloc((size_t)KCH * N * 2);
    unsigned* prefix32 = (unsigned*)alloc((size_t)KCH * N * 4);
    u16*      rank16   = (u16*)alloc((size_t)E * 2);
    u16*      xg       = (u16*)alloc((size_t)N * C * 2);   // bf16 dis.*x
    u16*      T1g      = (u16*)alloc((size_t)N * C * 2);   // bf16 dis.*T1

    const int B = 256;
    const int chunk = (E + KCH - 1) / KCH;
    const int G2 = (N + 511) / 512;   // 512-row scan blocks (<=256)

    hist_kernel<<<KCH, B, 0, stream>>>(row, cnt16, rank16, E, N, chunk);
    scanA_kernel<<<G2, B, 0, stream>>>(cnt16, cnttot, bsum, N, KCH);
    scanB_kernel<<<1, B, 0, stream>>>(bsum, rowptr, G2, N);
    scanC_kernel<<<G2, B, 0, stream>>>(cnt16, cnttot, bsum, rowptr, prefix32, N, KCH);
    scatter_kernel<<<KCH, B, 0, stream>>>(row, col, ew, rank16, prefix32, ewc,
                                          E, N, chunk);
    degdis_kernel<<<(N + 255) / 256, B, 0, stream>>>(rowptr, ewc, x, dis, xg, N);

    int spmm_blocks = (int)(((long long)N * 64 + B - 1) / B);
    spmm_csr_kernel<<<spmm_blocks, B, 0, stream>>>(rowptr, ewc, dis, xg, T1, T1g, N, 1);
    spmm_csr_kernel<<<spmm_blocks, B, 0, stream>>>(rowptr, ewc, dis, T1g, P, T1g, N, 0);

    final_gemm_kernel<<<(N + 63) / 64, B, 0, stream>>>(x, T1, P, W, b, out, N);
}

// Round 9
// 205.545 us; speedup vs baseline: 1.4335x; 1.4335x over previous
//
#include <hip/hip_runtime.h>
#include <hip/hip_bf16.h>

#define C 64   // C_IN == C_OUT == 64
#define NCOPY 8
#define FXSCALE 16777216.0f            // 2^24
#define LOW44 ((1ULL << 44) - 1)

typedef unsigned short u16;

__device__ __forceinline__ u16 f2bf_rne(float v) {
    unsigned u = __float_as_uint(v);
    u += 0x7FFFu + ((u >> 16) & 1u);
    return (u16)(u >> 16);
}
__device__ __forceinline__ float bf2f(u16 u) {
    return __uint_as_float((unsigned)u << 16);
}

// --- Kernel 1: fused histogram (x4 unrolled) + x->bf16 convert.
// One u64 atomic per edge: bits [44:63] = count, [0:43] = fixed-point sum(ew).
// Return value's high bits = this edge's rank within (copy,row).
__global__ __launch_bounds__(256) void hist8_kernel(const int* __restrict__ row,
                                                    const float* __restrict__ ew,
                                                    unsigned long long* __restrict__ cd8,
                                                    int* __restrict__ rank,
                                                    const float* __restrict__ x,
                                                    u16* __restrict__ xh,
                                                    int E, int N, int total4, int nthreads) {
    int t = threadIdx.x;
    int base = blockIdx.x * 1024;
    int copy = blockIdx.x & (NCOPY - 1);
    size_t cb = (size_t)copy * N;

    unsigned long long old[4];
    int e[4];
#pragma unroll
    for (int u = 0; u < 4; u++) {
        e[u] = base + u * 256 + t;
        if (e[u] < E) {
            int r = row[e[u]];
            unsigned long long fx = (unsigned long long)__float2uint_rn(ew[e[u]] * FXSCALE);
            unsigned long long inc = (1ULL << 44) | fx;
            old[u] = atomicAdd(&cd8[cb + r], inc);
        }
    }
#pragma unroll
    for (int u = 0; u < 4; u++) {
        if (e[u] < E) rank[e[u]] = (int)(old[u] >> 44);
    }

    // fused x -> bf16 convert (grid-stride)
    int gtid = blockIdx.x * 256 + t;
    for (int i = gtid; i < total4; i += nthreads) {
        float4 v = *(const float4*)(x + (size_t)i * 4);
        ushort4 o;
        o.x = f2bf_rne(v.x); o.y = f2bf_rne(v.y);
        o.z = f2bf_rne(v.z); o.w = f2bf_rne(v.w);
        *(ushort4*)(xh + (size_t)i * 4) = o;
    }
}

// --- Scan phase A: reduce 8 copies -> cnt, dis; per-block sums of cnt ---
__global__ __launch_bounds__(256) void scanA_kernel(const unsigned long long* __restrict__ cd8,
                                                    int* __restrict__ cnt,
                                                    float* __restrict__ dis,
                                                    int* __restrict__ bsum, int N) {
    __shared__ int s[256];
    int t = threadIdx.x;
    int i = blockIdx.x * 256 + t;
    int cv = 0;
    unsigned long long dfx = 0;
    if (i < N) {
#pragma unroll
        for (int c = 0; c < NCOPY; c++) {
            unsigned long long v = cd8[(size_t)c * N + i];
            cv += (int)(v >> 44);
            dfx += (v & LOW44);
        }
        cnt[i] = cv;
        float dv = (float)dfx * (1.0f / FXSCALE);
        dis[i] = (dv > 0.0f) ? rsqrtf(dv) : 0.0f;
    }
    s[t] = cv;
    __syncthreads();
    for (int off = 128; off > 0; off >>= 1) {
        if (t < off) s[t] += s[t + off];
        __syncthreads();
    }
    if (t == 0) bsum[blockIdx.x] = s[0];
}

// --- Scan phase B: exclusive scan of G (<=256) block sums; writes rowptr[N] ---
__global__ __launch_bounds__(256) void scanB_kernel(int* __restrict__ bsum,
                                                    int* __restrict__ rowptr,
                                                    int G, int N) {
    __shared__ int s[256];
    int t = threadIdx.x;
    int v = (t < G) ? bsum[t] : 0;
    s[t] = v;
    __syncthreads();
    for (int off = 1; off < 256; off <<= 1) {
        int u = (t >= off) ? s[t - off] : 0;
        __syncthreads();
        s[t] += u;
        __syncthreads();
    }
    if (t < G) bsum[t] = s[t] - v;          // exclusive block prefix
    if (t == 255) rowptr[N] = s[255];       // total edge count
}

// --- Scan phase C: rowptr + per-copy start slots (atomic-free scatter prep) ---
__global__ __launch_bounds__(256) void scanC_kernel(const int* __restrict__ cnt,
                                                    const unsigned long long* __restrict__ cd8,
                                                    int* __restrict__ start8,
                                                    const int* __restrict__ bsum,
                                                    int* __restrict__ rowptr, int N) {
    __shared__ int s[256];
    int t = threadIdx.x;
    int i = blockIdx.x * 256 + t;
    int v = (i < N) ? cnt[i] : 0;
    s[t] = v;
    __syncthreads();
    for (int off = 1; off < 256; off <<= 1) {
        int u = (t >= off) ? s[t - off] : 0;
        __syncthreads();
        s[t] += u;
        __syncthreads();
    }
    if (i < N) {
        int rp = bsum[blockIdx.x] + s[t] - v;  // exclusive prefix
        rowptr[i] = rp;
        int run = rp;
#pragma unroll
        for (int c = 0; c < NCOPY; c++) {
            int tmp = (int)(cd8[(size_t)c * N + i] >> 44);
            start8[(size_t)c * N + i] = run;   // start slot for this copy
            run += tmp;
        }
    }
}

// --- Kernel 4: atomic-free scatter (x4 unrolled, same copy mapping as hist) ---
__global__ __launch_bounds__(256) void scatter_kernel(const int* __restrict__ row,
                                                      const int* __restrict__ col,
                                                      const float* __restrict__ ew,
                                                      const float* __restrict__ dis,
                                                      const int* __restrict__ start8,
                                                      const int* __restrict__ rank,
                                                      float2* __restrict__ ewc,
                                                      int E, int N) {
    int t = threadIdx.x;
    int base = blockIdx.x * 1024;
    int copy = blockIdx.x & (NCOPY - 1);
    size_t cb = (size_t)copy * N;
#pragma unroll
    for (int u = 0; u < 4; u++) {
        int e = base + u * 256 + t;
        if (e < E) {
            int r = row[e];
            int c = col[e];
            float wv = -dis[r] * ew[e] * dis[c];
            int pos = start8[cb + r] + rank[e];
            ewc[pos] = make_float2(wv, __int_as_float(c));
        }
    }
}

// --- Kernel 5: CSR SpMM, 2 edges per wave (half-wave per edge), bf16x2 gathers.
// lane = (half, chpair): half-wave h processes edges j+h; lane loads one u32
// (2 bf16 channels). One VMEM instruction serves 2 edges (256B).
__global__ __launch_bounds__(256) void spmm_csr_kernel(
        const int* __restrict__ rowptr,
        const float2* __restrict__ ewc,
        const unsigned* __restrict__ h32,   // bf16x2 [N][32]
        float* __restrict__ out32,          // fp32 [N][C]
        unsigned* __restrict__ outbf,       // bf16x2 [N][32]
        int N) {
    int wid = (blockIdx.x * blockDim.x + threadIdx.x) >> 6;  // row id
    int lane = threadIdx.x & 63;
    if (wid >= N) return;
    int half = lane >> 5;        // which edge of the pair
    int cp   = lane & 31;        // channel pair 0..31
    int beg = rowptr[wid];
    int end = rowptr[wid + 1];
    float ax0 = 0.f, ay0 = 0.f, ax1 = 0.f, ay1 = 0.f;
    float ax2 = 0.f, ay2 = 0.f, ax3 = 0.f, ay3 = 0.f;
    for (int base = beg; base < end; base += 64) {
        int idx = base + lane;
        // zero-pad: w=0, col=0 -> harmless gather of row 0
        float2 ed = (idx < end) ? ewc[idx] : make_float2(0.0f, __int_as_float(0));
        int cnt = end - base; if (cnt > 64) cnt = 64;
        for (int j = 0; j < cnt; j += 8) {
            int s0 = j + half;
            int s1 = j + 2 + half;
            int s2 = j + 4 + half;
            int s3 = j + 6 + half;
            float w0 = __shfl(ed.x, s0);
            int   c0 = __shfl(__float_as_int(ed.y), s0);
            float w1 = __shfl(ed.x, s1);
            int   c1 = __shfl(__float_as_int(ed.y), s1);
            float w2 = __shfl(ed.x, s2);
            int   c2 = __shfl(__float_as_int(ed.y), s2);
            float w3 = __shfl(ed.x, s3);
            int   c3 = __shfl(__float_as_int(ed.y), s3);
            unsigned hv0 = h32[(size_t)c0 * 32 + cp];
            unsigned hv1 = h32[(size_t)c1 * 32 + cp];
            unsigned hv2 = h32[(size_t)c2 * 32 + cp];
            unsigned hv3 = h32[(size_t)c3 * 32 + cp];
            ax0 = fmaf(w0, bf2f((u16)(hv0 & 0xffffu)), ax0);
            ay0 = fmaf(w0, bf2f((u16)(hv0 >> 16)),     ay0);
            ax1 = fmaf(w1, bf2f((u16)(hv1 & 0xffffu)), ax1);
            ay1 = fmaf(w1, bf2f((u16)(hv1 >> 16)),     ay1);
            ax2 = fmaf(w2, bf2f((u16)(hv2 & 0xffffu)), ax2);
            ay2 = fmaf(w2, bf2f((u16)(hv2 >> 16)),     ay2);
            ax3 = fmaf(w3, bf2f((u16)(hv3 & 0xffffu)), ax3);
            ay3 = fmaf(w3, bf2f((u16)(hv3 >> 16)),     ay3);
        }
    }
    float ax = (ax0 + ax1) + (ax2 + ax3);
    float ay = (ay0 + ay1) + (ay2 + ay3);
    // combine the two half-waves
    float bx = __shfl(ax, cp + 32);
    float by = __shfl(ay, cp + 32);
    if (half == 0) {
        float rx = ax + bx;
        float ry = ay + by;
        *(float2*)(out32 + (size_t)wid * C + 2 * cp) = make_float2(rx, ry);
        unsigned pk = (unsigned)f2bf_rne(rx) | ((unsigned)f2bf_rne(ry) << 16);
        outbf[(size_t)wid * 32 + cp] = pk;
    }
}

// --- Kernel 6: fused dense epilogue as register-tiled GEMM ---
// out = relu([x | T1 | 2P-x] @ Wcat + b), Wcat = [192][64] (W row-major)
__global__ __launch_bounds__(256) void final_gemm_kernel(
        const float* __restrict__ x,
        const float* __restrict__ T1,
        const float* __restrict__ P,
        const float* __restrict__ W,   // [192][64] row-major
        const float* __restrict__ b,
        float* __restrict__ out, int N) {
    __shared__ float As[16][64];  // [k][node]
    __shared__ float Ws[16][64];  // [k][col]

    int t  = threadIdx.x;
    int tx = t & 15;
    int ty = t >> 4;
    int n0 = blockIdx.x * 64;

    int sn = t >> 2;
    int skb = (t & 3) * 4;

    float acc[4][4];
#pragma unroll
    for (int i = 0; i < 4; i++)
#pragma unroll
        for (int j = 0; j < 4; j++) acc[i][j] = 0.0f;

#pragma unroll 1
    for (int s = 0; s < 12; s++) {
        float4 wv = *(const float4*)(W + s * 1024 + t * 4);
        int nn = n0 + sn;
        float4 av = make_float4(0.f, 0.f, 0.f, 0.f);
        if (nn < N) {
            if (s < 4) {
                av = *(const float4*)(x + (size_t)nn * C + s * 16 + skb);
            } else if (s < 8) {
                av = *(const float4*)(T1 + (size_t)nn * C + (s - 4) * 16 + skb);
            } else {
                float4 pv = *(const float4*)(P + (size_t)nn * C + (s - 8) * 16 + skb);
                float4 xv = *(const float4*)(x + (size_t)nn * C + (s - 8) * 16 + skb);
                av = make_float4(2.0f * pv.x - xv.x, 2.0f * pv.y - xv.y,
                                 2.0f * pv.z - xv.z, 2.0f * pv.w - xv.w);
            }
        }
        __syncthreads();
        {
            int wk = (t * 4) >> 6;
            int wc = (t * 4) & 63;
            *(float4*)&Ws[wk][wc] = wv;
        }
        As[skb + 0][sn] = av.x;
        As[skb + 1][sn] = av.y;
        As[skb + 2][sn] = av.z;
        As[skb + 3][sn] = av.w;
        __syncthreads();

#pragma unroll
        for (int kk = 0; kk < 16; kk++) {
            float4 a4 = *(const float4*)&As[kk][ty * 4];
            float4 w4 = *(const float4*)&Ws[kk][tx * 4];
            float ar[4] = {a4.x, a4.y, a4.z, a4.w};
            float wr[4] = {w4.x, w4.y, w4.z, w4.w};
#pragma unroll
            for (int i = 0; i < 4; i++)
#pragma unroll
                for (int j = 0; j < 4; j++)
                    acc[i][j] = fmaf(ar[i], wr[j], acc[i][j]);
        }
    }

    float4 bv = *(const float4*)(b + tx * 4);
    float br[4] = {bv.x, bv.y, bv.z, bv.w};
#pragma unroll
    for (int i = 0; i < 4; i++) {
        int node = n0 + ty * 4 + i;
        if (node < N) {
            float4 o;
            o.x = fmaxf(acc[i][0] + br[0], 0.0f);
            o.y = fmaxf(acc[i][1] + br[1], 0.0f);
            o.z = fmaxf(acc[i][2] + br[2], 0.0f);
            o.w = fmaxf(acc[i][3] + br[3], 0.0f);
            *(float4*)(out + (size_t)node * C + tx * 4) = o;
        }
    }
}

extern "C" void kernel_launch(void* const* d_in, const int* in_sizes, int n_in,
                              void* d_out, int out_size, void* d_ws, size_t ws_size,
                              hipStream_t stream) {
    const float* x  = (const float*)d_in[0];
    const int*   ei = (const int*)d_in[1];
    const float* ew = (const float*)d_in[2];
    const float* W  = (const float*)d_in[3];
    const float* b  = (const float*)d_in[4];
    float* out = (float*)d_out;

    const int N = in_sizes[0] / C;
    const int E = in_sizes[2];
    const int* row = ei;        // edge_index[0]
    const int* col = ei + E;    // edge_index[1]

    char* ws = (char*)d_ws;
    size_t off = 0;
    auto alloc = [&](size_t bytes) {
        void* p = ws + off;
        off = (off + bytes + 255) & ~(size_t)255;
        return p;
    };
    float*  dis    = (float*)alloc((size_t)N * 4);
    int*    cnt    = (int*)alloc((size_t)N * 4);
    int*    rowptr = (int*)alloc((size_t)(N + 1) * 4);
    float2* ewc    = (float2*)alloc((size_t)E * 8);
    float*  T1     = (float*)alloc((size_t)N * C * 4);
    float*  P      = (float*)alloc((size_t)N * C * 4);
    int*    bsum   = (int*)alloc((size_t)256 * 4);
    unsigned long long* cd8 = (unsigned long long*)alloc((size_t)NCOPY * N * 8);
    int*    start8 = (int*)alloc((size_t)NCOPY * N * 4);
    int*    rank   = (int*)alloc((size_t)E * 4);
    u16*    xh     = (u16*)alloc((size_t)N * C * 2);
    u16*    T1h    = (u16*)alloc((size_t)N * C * 2);
    u16*    Ph     = (u16*)alloc((size_t)N * C * 2);  // unused sink

    hipMemsetAsync(cd8, 0, (size_t)NCOPY * N * 8, stream);

    const int B = 256;
    const int G = (N + B - 1) / B;  // 196 <= 256

    int histBlocks = (E + 1023) / 1024;
    int total4 = N * C / 4;
    hist8_kernel<<<histBlocks, B, 0, stream>>>(row, ew, cd8, rank, x, xh,
                                               E, N, total4, histBlocks * B);
    scanA_kernel<<<G, B, 0, stream>>>(cd8, cnt, dis, bsum, N);
    scanB_kernel<<<1, B, 0, stream>>>(bsum, rowptr, G, N);
    scanC_kernel<<<G, B, 0, stream>>>(cnt, cd8, start8, bsum, rowptr, N);
    scatter_kernel<<<histBlocks, B, 0, stream>>>(row, col, ew, dis, start8,
                                                 rank, ewc, E, N);

    int spmm_blocks = (int)(((long long)N * 64 + B - 1) / B);
    spmm_csr_kernel<<<spmm_blocks, B, 0, stream>>>(rowptr, ewc, (const unsigned*)xh,
                                                   T1, (unsigned*)T1h, N);
    spmm_csr_kernel<<<spmm_blocks, B, 0, stream>>>(rowptr, ewc, (const unsigned*)T1h,
                                                   P, (unsigned*)Ph, N);

    final_gemm_kernel<<<(N + 63) / 64, B, 0, stream>>>(x, T1, P, W, b, out, N);
}